// Round 10
// baseline (520.405 us; speedup 1.0000x reference)
//
#include <hip/hip_runtime.h>

typedef unsigned short u16;
typedef short v8s __attribute__((ext_vector_type(8)));
typedef _Float16 v8h __attribute__((ext_vector_type(8)));
typedef float v4f __attribute__((ext_vector_type(4)));

#define BB 4
#define LL 2048
#define DD 1024
#define NH 16
#define HD 64
// 0.125 (1/sqrt(64)) * log2(e): puts attention logits in exp2 domain
#define QSCALE 0.18033688011112042f
#define PAD 72  // LDS pad for attn tiles (not used by global_load_lds tiles)

__device__ __forceinline__ float bf2f(u16 u) {
  union { unsigned int i; float f; } v; v.i = ((unsigned int)u) << 16; return v.f;
}
__device__ __forceinline__ u16 f2bf(float f) {
  union { float f; unsigned int i; } v; v.f = f;
  unsigned int u = v.i;
  return (u16)((u + 0x7fffu + ((u >> 16) & 1u)) >> 16);
}
__device__ __forceinline__ u16 f2h(float f) {
  union { _Float16 h; u16 u; } v; v.h = (_Float16)f; return v.u;
}
// async global->LDS, 16B/lane. LDS dest = wave-uniform base + lane*16.
__device__ __forceinline__ void gl_lds16(const u16* g, u16* l) {
  __builtin_amdgcn_global_load_lds(
      (const __attribute__((address_space(1))) void*)g,
      (__attribute__((address_space(3))) void*)l, 16, 0, 0);
}

// ---------------- sentinel fill (contract-violation signal), fp32 ----------------
__global__ __launch_bounds__(256) void fill_val(float* __restrict__ out, float v, int n) {
  int i = blockIdx.x * 256 + threadIdx.x;
  if (i < n) out[i] = v;
}

// ---------------- cast x fp32 -> bf16 --------------------------------------------
__global__ __launch_bounds__(256) void cast_x(
    const float* __restrict__ x, u16* __restrict__ Xb) {
  int i = (blockIdx.x * 256 + threadIdx.x) * 8;
  float4 a = *(const float4*)(x + i);
  float4 b = *(const float4*)(x + i + 4);
  v8s v;
  v[0] = (short)f2bf(a.x); v[1] = (short)f2bf(a.y);
  v[2] = (short)f2bf(a.z); v[3] = (short)f2bf(a.w);
  v[4] = (short)f2bf(b.x); v[5] = (short)f2bf(b.y);
  v[6] = (short)f2bf(b.z); v[7] = (short)f2bf(b.w);
  *(v8s*)(Xb + i) = v;
}

// ---------------- weight transpose: W[k][n] fp32 -> WT[n][k] bf16, 4 mats --------
__global__ __launch_bounds__(256) void transpose_w(
    const float* __restrict__ Wq, const float* __restrict__ Wk,
    const float* __restrict__ Wv, const float* __restrict__ Wo,
    u16* __restrict__ WT) {
  __shared__ u16 tile[64][72];
  int z = blockIdx.z;
  const float* src = (z == 0) ? Wq : (z == 1) ? Wk : (z == 2) ? Wv : Wo;
  u16* dst = WT + (size_t)z * DD * DD;
  int n0 = blockIdx.x * 64, k0 = blockIdx.y * 64;
  int tid = threadIdx.x;
#pragma unroll
  for (int i = 0; i < 2; ++i) {
    int cid = i * 256 + tid;
    int r = cid >> 3, c = (cid & 7) * 8;
    const float* sp = src + (size_t)(k0 + r) * DD + n0 + c;
    float4 a = *(const float4*)sp;
    float4 b = *(const float4*)(sp + 4);
    tile[r][c + 0] = f2bf(a.x); tile[r][c + 1] = f2bf(a.y);
    tile[r][c + 2] = f2bf(a.z); tile[r][c + 3] = f2bf(a.w);
    tile[r][c + 4] = f2bf(b.x); tile[r][c + 5] = f2bf(b.y);
    tile[r][c + 6] = f2bf(b.z); tile[r][c + 7] = f2bf(b.w);
  }
  __syncthreads();
#pragma unroll
  for (int i = 0; i < 2; ++i) {
    int cid = i * 256 + tid;
    int r = cid >> 3, c = (cid & 7) * 8;
    v8s v;
#pragma unroll
    for (int j = 0; j < 8; ++j) v[j] = (short)tile[c + j][r];
    *(v8s*)(dst + (size_t)(n0 + r) * DD + k0 + c) = v;
  }
}

// ---------------- 128x128 GEMM, global_load_lds staging --------------------------
// Fused N: bx = blockIdx.x + nbase in [0,32): mode = bx>>3 (1024 cols/mode).
// mode 0: Xb @ WqT (scaled) -> Qb[b,h,l,d] bf16   mode 1: -> Kb[b,h,l,d] bf16
// mode 2: Xb @ WvT -> Vtb[b,h,d,l] f16            mode 3: ctx @ WoT + bo -> projb
// Epilogue stores are nontemporal: 48MB output stream must not evict L2
// (this GEMM is beyond-L2-traffic-bound, not staging-bound).
__global__ __launch_bounds__(256) void gemm128(
    const u16* __restrict__ Xb, const u16* __restrict__ CTX,
    const u16* __restrict__ WT,
    const float* __restrict__ bq, const float* __restrict__ bk,
    const float* __restrict__ bv, const float* __restrict__ bo,
    u16* __restrict__ Qb, u16* __restrict__ Kb, u16* __restrict__ Vtb,
    u16* __restrict__ projb, int nbase) {
  __shared__ __align__(16) u16 As[128 * 64];  // [m][k], no pad (async-copy contract)
  __shared__ __align__(16) u16 Bs[128 * 64];  // [n][k]

  int tid = threadIdx.x;
  int wave = tid >> 6, lane = tid & 63, quad = lane >> 4, l15 = lane & 15;
  int wr = wave >> 1, wc = wave & 1;  // 2x2 wave grid, 64x64 each
  int bx = blockIdx.x + nbase;
  int mode = bx >> 3;
  int n0g = bx * 128;
  int m0 = blockIdx.y * 128;
  const float* bias = (mode == 0) ? bq : (mode == 1) ? bk : (mode == 2) ? bv : bo;

  const u16* Ab = ((mode == 3) ? CTX : Xb) + (size_t)m0 * DD;
  const u16* Bb = WT + (size_t)n0g * DD;
  int lrow = lane >> 3, lcol = (lane & 7) * 8;

  v4f acc[4][4] = {};

  for (int kt = 0; kt < DD / 64; ++kt) {
    int k0 = kt * 64;
    __syncthreads();
#pragma unroll
    for (int j = 0; j < 4; ++j) {
      int seg = wave * 4 + j;  // 16 segments of 8 rows
      gl_lds16(Ab + (size_t)(seg * 8 + lrow) * DD + k0 + lcol, &As[seg * 512]);
      gl_lds16(Bb + (size_t)(seg * 8 + lrow) * DD + k0 + lcol, &Bs[seg * 512]);
    }
    __syncthreads();

#pragma unroll
    for (int cc = 0; cc < 2; ++cc) {
      v8s a[4], b[4];
#pragma unroll
      for (int i = 0; i < 4; ++i)
        a[i] = *(const v8s*)&As[(wr * 64 + i * 16 + l15) * 64 + cc * 32 + quad * 8];
#pragma unroll
      for (int j = 0; j < 4; ++j)
        b[j] = *(const v8s*)&Bs[(wc * 64 + j * 16 + l15) * 64 + cc * 32 + quad * 8];
#pragma unroll
      for (int i = 0; i < 4; ++i)
#pragma unroll
        for (int j = 0; j < 4; ++j)
          acc[i][j] = __builtin_amdgcn_mfma_f32_16x16x32_bf16(a[i], b[j], acc[i][j], 0, 0, 0);
    }
  }

#pragma unroll
  for (int j = 0; j < 4; ++j) {
    int n_g = n0g + wc * 64 + j * 16 + l15;
    int n = n_g & (DD - 1);
    float bias_v = bias[n];
#pragma unroll
    for (int i = 0; i < 4; ++i)
#pragma unroll
      for (int r = 0; r < 4; ++r) {
        int m = m0 + wr * 64 + i * 16 + quad * 4 + r;
        float v = acc[i][j][r] + bias_v;
        if (mode == 3) {
          __builtin_nontemporal_store(f2bf(v), &projb[(size_t)m * DD + n]);
        } else {
          int b = m >> 11, l = m & (LL - 1);
          int h = n >> 6, d = n & 63;
          if (mode == 0) {
            __builtin_nontemporal_store(f2bf(v * QSCALE),
                &Qb[((size_t)(b * NH + h) * LL + l) * HD + d]);
          } else if (mode == 1) {
            __builtin_nontemporal_store(f2bf(v),
                &Kb[((size_t)(b * NH + h) * LL + l) * HD + d]);
          } else {
            __builtin_nontemporal_store(f2h(v),
                &Vtb[((size_t)(b * NH + h) * HD + d) * LL + l]);
          }
        }
      }
  }
}

// ---------------- flash attention ------------------------------------------------
// p = exp2(s) directly (logits |s|<~10; f16 overflow needs s>16 ~ 11 sigma).
// P and V in f16 (more mantissa than bf16; p in [2^-24, 2^9] representable).
// Softmax denominator = P x ones via MFMA (idle pipe), consistent with PV's
// rounded-f16 P. 128 queries per block: 4 waves x 2 strips of 16.
__global__ __launch_bounds__(256) void attn(
    const u16* __restrict__ Qb, const u16* __restrict__ Kb,
    const u16* __restrict__ Vtb, u16* __restrict__ ctx) {
  __shared__ __align__(16) u16 Ks[64 * PAD];       // [key][d]   bf16
  __shared__ __align__(16) u16 Vs[64 * PAD];       // [d][key]   f16
  __shared__ __align__(16) u16 Ps[4][16 * PAD];    // per-wave [q][k] f16

  int tid = threadIdx.x;
  int wave = tid >> 6, lane = tid & 63, quad = lane >> 4, l15 = lane & 15;
  int bh = blockIdx.y;
  int q0 = blockIdx.x * 128;

  v8s aq[2][2];
#pragma unroll
  for (int s2 = 0; s2 < 2; ++s2) {
    const u16* Qp = Qb + ((size_t)bh * LL + q0 + s2 * 64 + wave * 16 + l15) * HD;
    aq[s2][0] = *(const v8s*)(Qp + quad * 8);
    aq[s2][1] = *(const v8s*)(Qp + 32 + quad * 8);
  }

  v8h ones;
#pragma unroll
  for (int j = 0; j < 8; ++j) ones[j] = (_Float16)1.0f;

  v4f o[2][4] = {};
  v4f osum[2] = {};  // row-sum accumulator (denominator), via MFMA

  const u16* Kbase = Kb + (size_t)bh * LL * HD;
  const u16* Vbase = Vtb + (size_t)bh * HD * LL;

  for (int kt = 0; kt < LL / 64; ++kt) {
    int k0 = kt * 64;
    __syncthreads();
#pragma unroll
    for (int i = 0; i < 2; ++i) {
      int cid = i * 256 + tid;
      int r = cid >> 3, c = (cid & 7) * 8;
      *(v8s*)&Ks[r * PAD + c] = *(const v8s*)(Kbase + (size_t)(k0 + r) * HD + c);
      *(v8s*)&Vs[r * PAD + c] = *(const v8s*)(Vbase + (size_t)r * LL + k0 + c);
    }
    __syncthreads();

    v4f s[2][4];
#pragma unroll
    for (int t = 0; t < 4; ++t) {
      v8s b0 = *(const v8s*)&Ks[(t * 16 + l15) * PAD + quad * 8];
      v8s b1 = *(const v8s*)&Ks[(t * 16 + l15) * PAD + 32 + quad * 8];
#pragma unroll
      for (int s2 = 0; s2 < 2; ++s2) {
        v4f z = {};
        z = __builtin_amdgcn_mfma_f32_16x16x32_bf16(aq[s2][0], b0, z, 0, 0, 0);
        s[s2][t] = __builtin_amdgcn_mfma_f32_16x16x32_bf16(aq[s2][1], b1, z, 0, 0, 0);
      }
    }

#pragma unroll
    for (int s2 = 0; s2 < 2; ++s2) {
#pragma unroll
      for (int t = 0; t < 4; ++t)
#pragma unroll
        for (int r = 0; r < 4; ++r)
          Ps[wave][(quad * 4 + r) * PAD + t * 16 + l15] = f2h(exp2f(s[s2][t][r]));
      // wave-private LDS region: in-order DS pipe, no barrier needed
      v8h ap0 = *(const v8h*)&Ps[wave][l15 * PAD + quad * 8];
      v8h ap1 = *(const v8h*)&Ps[wave][l15 * PAD + 32 + quad * 8];
      osum[s2] = __builtin_amdgcn_mfma_f32_16x16x32_f16(ap0, ones, osum[s2], 0, 0, 0);
      osum[s2] = __builtin_amdgcn_mfma_f32_16x16x32_f16(ap1, ones, osum[s2], 0, 0, 0);
#pragma unroll
      for (int t = 0; t < 4; ++t) {
        v8h vb0 = *(const v8h*)&Vs[(t * 16 + l15) * PAD + quad * 8];
        v8h vb1 = *(const v8h*)&Vs[(t * 16 + l15) * PAD + 32 + quad * 8];
        o[s2][t] = __builtin_amdgcn_mfma_f32_16x16x32_f16(ap0, vb0, o[s2][t], 0, 0, 0);
        o[s2][t] = __builtin_amdgcn_mfma_f32_16x16x32_f16(ap1, vb1, o[s2][t], 0, 0, 0);
      }
    }
  }

  int b = bh >> 4, h = bh & 15;
#pragma unroll
  for (int s2 = 0; s2 < 2; ++s2)
#pragma unroll
    for (int r = 0; r < 4; ++r) {
      float inv = 1.f / osum[s2][r];  // all 16 cols of osum row are identical
      int l = q0 + s2 * 64 + wave * 16 + quad * 4 + r;
#pragma unroll
      for (int t = 0; t < 4; ++t)
        ctx[((size_t)(b * LL + l)) * DD + h * HD + t * 16 + l15] =
            f2bf(o[s2][t][r] * inv);
    }
}

// ---------------- residual + LayerNorm -> fp32 output ----------------------------
__global__ __launch_bounds__(256) void resid_ln(
    const float* __restrict__ x, const u16* __restrict__ projb,
    const float* __restrict__ gamma, const float* __restrict__ beta,
    float* __restrict__ out) {
  int row = blockIdx.x, tid = threadIdx.x;
  int base = tid * 4;
  float4 xv = *(const float4*)(x + (size_t)row * DD + base);
  ushort4 pv = *(const ushort4*)(projb + (size_t)row * DD + base);
  float y0 = xv.x + bf2f(pv.x), y1 = xv.y + bf2f(pv.y);
  float y2 = xv.z + bf2f(pv.z), y3 = xv.w + bf2f(pv.w);

  float s = y0 + y1 + y2 + y3;
  s += __shfl_xor(s, 1);  s += __shfl_xor(s, 2);  s += __shfl_xor(s, 4);
  s += __shfl_xor(s, 8);  s += __shfl_xor(s, 16); s += __shfl_xor(s, 32);
  __shared__ float red[8];
  int wv = tid >> 6, ln = tid & 63;
  if (ln == 0) red[wv] = s;
  __syncthreads();
  float mu = (red[0] + red[1] + red[2] + red[3]) * (1.f / DD);

  float d0 = y0 - mu, d1 = y1 - mu, d2 = y2 - mu, d3 = y3 - mu;
  float vv = d0 * d0 + d1 * d1 + d2 * d2 + d3 * d3;
  vv += __shfl_xor(vv, 1);  vv += __shfl_xor(vv, 2);  vv += __shfl_xor(vv, 4);
  vv += __shfl_xor(vv, 8);  vv += __shfl_xor(vv, 16); vv += __shfl_xor(vv, 32);
  if (ln == 0) red[4 + wv] = vv;
  __syncthreads();
  float var = (red[4] + red[5] + red[6] + red[7]) * (1.f / DD);
  float rstd = rsqrtf(var + 1e-5f);

  float4 gv = *(const float4*)(gamma + base);
  float4 bv = *(const float4*)(beta + base);
  v4f ov;
  ov[0] = d0 * rstd * gv.x + bv.x;
  ov[1] = d1 * rstd * gv.y + bv.y;
  ov[2] = d2 * rstd * gv.z + bv.z;
  ov[3] = d3 * rstd * gv.w + bv.w;
  __builtin_nontemporal_store(ov, (v4f*)(out + (size_t)row * DD + base));
}

extern "C" void kernel_launch(void* const* d_in, const int* in_sizes, int n_in,
                              void* d_out, int out_size, void* d_ws, size_t ws_size,
                              hipStream_t stream) {
  (void)ws_size;
  float* out = (float*)d_out;

  bool ok = (n_in == 11) && (out_size == BB * LL * DD);
  if (ok) {
    const int want[11] = {BB * LL * DD, DD * DD, DD, DD * DD, DD, DD * DD,
                          DD, DD * DD, DD, DD, DD};
    for (int i = 0; i < 11; ++i) ok = ok && (in_sizes[i] == want[i]);
  }
  if (!ok) {
    fill_val<<<(out_size + 255) / 256, 256, 0, stream>>>(out, 1000.0f, out_size);
    return;
  }

  const float* x     = (const float*)d_in[0];
  const float* Wq    = (const float*)d_in[1];
  const float* bq    = (const float*)d_in[2];
  const float* Wk    = (const float*)d_in[3];
  const float* bk    = (const float*)d_in[4];
  const float* Wv    = (const float*)d_in[5];
  const float* bv    = (const float*)d_in[6];
  const float* Wo    = (const float*)d_in[7];
  const float* bo    = (const float*)d_in[8];
  const float* gamma = (const float*)d_in[9];
  const float* beta  = (const float*)d_in[10];

  // ws: WT 8MB | Xb 16 | Qb 16 | Kb 16 | Vtb 16  (72MB)
  // ctx staged as bf16 in d_out (fp32 buffer, fully rewritten by resid_ln);
  // projb aliases Xb (dead after QKV GEMM).
  char* ws = (char*)d_ws;
  u16* WT   = (u16*)(ws);
  u16* Xb   = (u16*)(ws + (size_t)8 * 1024 * 1024);
  u16* Qb   = (u16*)(ws + (size_t)24 * 1024 * 1024);
  u16* Kb   = (u16*)(ws + (size_t)40 * 1024 * 1024);
  u16* Vtb  = (u16*)(ws + (size_t)56 * 1024 * 1024);
  u16* ctxO = (u16*)d_out;
  u16* projb = Xb;

  cast_x<<<4096, 256, 0, stream>>>(x, Xb);
  transpose_w<<<dim3(16, 16, 4), 256, 0, stream>>>(Wq, Wk, Wv, Wo, WT);
  gemm128<<<dim3(24, 64), 256, 0, stream>>>(Xb, ctxO, WT, bq, bk, bv, bo,
                                            Qb, Kb, Vtb, projb, 0);
  attn<<<dim3(LL / 128, BB * NH), 256, 0, stream>>>(Qb, Kb, Vtb, ctxO);
  gemm128<<<dim3(8, 64), 256, 0, stream>>>(Xb, ctxO, WT, bq, bk, bv, bo,
                                           Qb, Kb, Vtb, projb, 24);
  resid_ln<<<8192, 256, 0, stream>>>(x, projb, gamma, beta, out);
}